// Round 13
// baseline (1144.699 us; speedup 1.0000x reference)
//
#include <hip/hip_runtime.h>
#include <cstdint>

typedef __bf16 bf16_t;
typedef __bf16 bf16x8 __attribute__((ext_vector_type(8)));
typedef float  f32x4  __attribute__((ext_vector_type(4)));

// Workspace layout
#define XPAD_ELEMS (32UL*58*58*128)      // padded NHWC bf16 input
#define WPERM_OFF  (XPAD_ELEMS*2)        // bytes
#define WPERM_ELEMS (256UL*9*128)        // 294912
#define WS_NEEDED  (WPERM_OFF + WPERM_ELEMS*2)

// async global->LDS, 16B per lane; lds dest is wave-uniform base + lane*16
__device__ __forceinline__ void async16(const bf16_t* g, const bf16_t* l) {
  __builtin_amdgcn_global_load_lds(
      (const __attribute__((address_space(1))) void*)g,
      (__attribute__((address_space(3))) void*)l, 16, 0, 0);
}

// ------- merged prepass: x transpose (blocks 0..1855) + weight prepack (1856..3007) ----
// xform: NCHW f32 -> padded NHWC bf16 (32,58,58,128), borders zeroed.
// wperm: OIHW f32 -> Wpk[t][kc][o][e]; value = wt[o][c=ci*32+kc*8+e][tap rs], ci=t&3, rs=t>>2.
__global__ __launch_bounds__(256) void k_pre(const float* __restrict__ x,
                                             const float* __restrict__ wt,
                                             bf16_t* __restrict__ Xp,
                                             bf16_t* __restrict__ Wp) {
  const int bid = (int)blockIdx.x;
  const int t = threadIdx.x;
  if (bid >= 1856) {                      // ---- weight prepack ----
    int i = (bid - 1856) * 256 + t;
    if (i >= 294912) return;
    int e  = i & 7;
    int o  = (i >> 3) & 255;
    int kc = (i >> 11) & 3;
    int tt = i >> 13;
    int ci = tt & 3, rs = tt >> 2;
    int c  = ci * 32 + kc * 8 + e;
    Wp[i] = (bf16_t)wt[o * 1152 + c * 9 + rs];
    return;
  }
  // ---- x transform ----
  const int n = bid / 58, hp = bid % 58;
  bf16_t* drow = Xp + ((size_t)n * 58 + hp) * 58 * 128;
  uint4 z; z.x = z.y = z.z = z.w = 0;
  if (hp == 0 || hp == 57) {             // full border row
    uint4* p = (uint4*)drow;
    for (int i = t; i < 928; i += 256) p[i] = z;
    return;
  }
  if (t < 32) {                           // border pixels w=0 and w=57
    uint4* p0 = (uint4*)drow;
    uint4* p1 = (uint4*)(drow + 57 * 128);
    if (t < 16) p0[t] = z; else p1[t - 16] = z;
  }
  const int h = hp - 1;
  const float* src = x + (size_t)n * 401408 + h * 56;   // + c*3136 + w
  __shared__ float lds[128 * 57];
  for (int i = t; i < 7168; i += 256) {   // 128 c * 56 w
    int c = i / 56;
    int w = i - c * 56;
    lds[c * 57 + w] = src[(size_t)c * 3136 + w];
  }
  __syncthreads();
  bf16_t* dst = drow + 128;               // w starts at 1
  for (int i = t; i < 3584; i += 256) {   // pairs of channels
    int cp = i & 63, w = i >> 6;
    int c0 = cp * 2;
    unsigned short u0 = __builtin_bit_cast(unsigned short, (bf16_t)lds[c0 * 57 + w]);
    unsigned short u1 = __builtin_bit_cast(unsigned short, (bf16_t)lds[(c0 + 1) * 57 + w]);
    *(unsigned int*)(dst + (size_t)w * 128 + c0) = (unsigned)u0 | ((unsigned)u1 << 16);
  }
}

// ---------------- naive fp32 fallback (only if ws too small) ----------------
__global__ void k_naive(const float* __restrict__ x, const float* __restrict__ wt,
                        const float* __restrict__ bs, float* __restrict__ out) {
  int idx = blockIdx.x * 256 + threadIdx.x;
  if (idx >= 25690112) return;
  int w = idx % 56; int tmp = idx / 56;
  int h = tmp % 56; tmp /= 56;
  int k = tmp % 256; int n = tmp / 256;
  float acc = bs[k];
  for (int c = 0; c < 128; ++c)
    for (int r = 0; r < 3; ++r) {
      int hy = h + r - 1; if ((unsigned)hy >= 56u) continue;
      for (int s = 0; s < 3; ++s) {
        int wx = w + s - 1; if ((unsigned)wx >= 56u) continue;
        acc += x[((size_t)(n * 128 + c) * 56 + hy) * 56 + wx] *
               wt[((size_t)(k * 128 + c) * 3 + r) * 3 + s];
      }
    }
  out[idx] = acc;
}

// ---------------- main conv: 5-row ring strip, 8 waves, ratio-4, 4 waves/SIMD ----
// Block = 8 waves (512 thr) = 256 out-ch x 224 px (4 output rows of one image).
// Wave (wv) = ch-group (wv>>1: 64ch) x px-group (wv&1: 112px): acc[4][7], 28 MFMA/step.
// B: ring of 5 padded rows (5x58x256B = 72.5KB). Rows h0..h0+4 staged up front;
//    row h0+5 streamed into ring slot 0 during tap-phase r=1 (slot 0's readers are
//    phase-0-only; barrier at phase entry + vmcnt(0)+barrier before phase 2).
// A: reg-resident distance-2 prefetch from L2-resident Wpk. 2 barriers in K-loop total.
__global__ __launch_bounds__(512, 4) void k_conv(const bf16_t* __restrict__ Xp,
                                                 const bf16_t* __restrict__ Wpk,
                                                 const float* __restrict__ bias,
                                                 float* __restrict__ out) {
  __shared__ bf16_t strip[4640 * 8];      // 74240 B: 5 ring rows x [58 px][chunk16][8ch]
  const int tid = threadIdx.x, lane = tid & 63, wv = tid >> 6;   // wv 0..7
  const int sid = (int)blockIdx.x;        // 0..447
  const int n   = sid / 14;
  const int h0  = (sid - n * 14) * 4;     // output-row origin (== Xp padded-row origin)

  // ---- initial stage: Xp rows h0..h0+4 -> ring slots 0..4 (4640 slots of 16B) ----
  const bf16_t* xbase = Xp + ((size_t)n * 58 + h0) * 58 * 128;
#pragma unroll
  for (int r = 0; r < 9; ++r) {
    int slot = r * 512 + tid;
    int pix = slot >> 4, cp = slot & 15;
    int hp = pix / 58, wp = pix - hp * 58;
    int cl = cp ^ (wp & 7);               // fetch logical chunk into phys slot
    async16(xbase + ((size_t)(hp * 58 + wp)) * 128 + cl * 8,
            strip + (r * 512 + wv * 64) * 8);
  }
  if (tid < 32) {                         // slots 4608..4639 (wave 0, exec-masked)
    int slot = 4608 + tid;
    int pix = slot >> 4, cp = slot & 15;
    int hp = pix / 58, wp = pix - hp * 58;
    int cl = cp ^ (wp & 7);
    async16(xbase + ((size_t)(hp * 58 + wp)) * 128 + cl * 8,
            strip + 4608 * 8);
  }

  // ---- per-lane geometry ----
  const int fr = lane & 15, fg = lane >> 4;
  const int pg = wv & 1, cg = wv >> 1;    // px-group (112px), ch-group (64ch)
  int ohv[7], owv[7];
#pragma unroll
  for (int ni = 0; ni < 7; ++ni) {
    int pq = pg * 112 + ni * 16 + fr;     // tile pixel 0..223
    ohv[ni] = pq / 56;                    // output row 0..3
    owv[ni] = pq - ohv[ni] * 56;          // output col 0..55
  }

  // ---- A fragments: wave-private 64 out-ch, reg-resident, distance-2 prefetch ----
  const bf16_t* wsrc = Wpk + fg * 2048 + (cg * 64 + fr) * 8;   // + t*8192 + mi*128
  bf16x8 areg[2][4];
#pragma unroll
  for (int mi = 0; mi < 4; ++mi) {
    areg[0][mi] = *(const bf16x8*)(wsrc + mi * 128);           // t=0
    areg[1][mi] = *(const bf16x8*)(wsrc + 8192 + mi * 128);    // t=1
  }

  asm volatile("s_waitcnt vmcnt(0)" ::: "memory");   // rows 0..4 + A landed
  __builtin_amdgcn_s_barrier();
  __builtin_amdgcn_sched_barrier(0);

  const bf16_t* xrow5 = Xp + ((size_t)n * 58 + h0 + 5) * 58 * 128;
  f32x4 acc[4][7] = {};

#pragma unroll
  for (int r = 0; r < 3; ++r) {           // tap-row phases; t = r*12 + q
    if (r == 1) {
      // all waves done reading ring slot 0 (phase 0); stream row h0+5 into it
      __builtin_amdgcn_s_barrier();
      __builtin_amdgcn_sched_barrier(0);
      {
        int wp = tid >> 4, cp = tid & 15;
        int cl = cp ^ (wp & 7);
        async16(xrow5 + (size_t)wp * 128 + cl * 8, strip + (wv * 64) * 8);
      }
      if (tid < 416) {
        int idx = 512 + tid;
        int wp = idx >> 4, cp = idx & 15;
        int cl = cp ^ (wp & 7);
        async16(xrow5 + (size_t)wp * 128 + cl * 8, strip + (512 + wv * 64) * 8);
      }
      __builtin_amdgcn_sched_barrier(0);
    }
    if (r == 2) {                          // row-5 writes landed everywhere
      asm volatile("s_waitcnt vmcnt(0)" ::: "memory");
      __builtin_amdgcn_s_barrier();
      __builtin_amdgcn_sched_barrier(0);
    }
    // per-phase row bases (ring slot = (oh + r) mod 5)
    int rowbase[7];
#pragma unroll
    for (int ni = 0; ni < 7; ++ni) {
      int sl = ohv[ni] + r;
      if (sl >= 5) sl -= 5;
      rowbase[ni] = sl * 7424 + owv[ni] * 128;
    }
    bf16x8 bcur[7], bnxt[7];
#pragma unroll
    for (int ni = 0; ni < 7; ++ni)        // q=0: ci=0, s=0
      bcur[ni] = *(const bf16x8*)&strip[rowbase[ni] + (fg ^ (fr & 7)) * 8];

#pragma unroll
    for (int q = 0; q < 12; ++q) {
      const int t  = r * 12 + q;
      const int pb = t & 1;
      if (q + 1 < 12) {                   // prefetch next step's B (within phase)
        const int ci1 = (q + 1) & 3, s1 = (q + 1) >> 2;
        const int cb1 = ci1 * 4;
#pragma unroll
        for (int ni = 0; ni < 7; ++ni) {
          int cph = (cb1 + fg) ^ ((fr + s1) & 7);
          bnxt[ni] = *(const bf16x8*)&strip[rowbase[ni] + s1 * 128 + cph * 8];
        }
      }
      __builtin_amdgcn_s_setprio(1);
#pragma unroll
      for (int mi = 0; mi < 4; ++mi)
#pragma unroll
        for (int ni = 0; ni < 7; ++ni)
          acc[mi][ni] = __builtin_amdgcn_mfma_f32_16x16x32_bf16(areg[pb][mi], bcur[ni], acc[mi][ni], 0, 0, 0);
      __builtin_amdgcn_s_setprio(0);
      if (t + 2 < 36) {                   // distance-2 A prefetch into freed slots
#pragma unroll
        for (int mi = 0; mi < 4; ++mi)
          areg[pb][mi] = *(const bf16x8*)(wsrc + (size_t)(t + 2) * 8192 + mi * 128);
      }
      if (q + 1 < 12) {
#pragma unroll
        for (int ni = 0; ni < 7; ++ni)    // SSA-renamed under unroll
          bcur[ni] = bnxt[ni];
      }
    }
  }

  // ---- epilogue: D reg j -> k = cg*64 + mi*16 + fg*4 + j, col = pixel fr ----
  const int mbase = cg * 64;
  float bv[4][4];
#pragma unroll
  for (int mi = 0; mi < 4; ++mi)
#pragma unroll
    for (int j = 0; j < 4; ++j)
      bv[mi][j] = bias[mbase + mi * 16 + fg * 4 + j];

#pragma unroll
  for (int ni = 0; ni < 7; ++ni) {
    float* ob = out + (size_t)n * 802816 + (h0 + ohv[ni]) * 56 + owv[ni];
#pragma unroll
    for (int mi = 0; mi < 4; ++mi) {
      int kb = mbase + mi * 16 + fg * 4;
#pragma unroll
      for (int j = 0; j < 4; ++j)
        ob[(size_t)(kb + j) * 3136] = acc[mi][ni][j] + bv[mi][j];
    }
  }
}

extern "C" void kernel_launch(void* const* d_in, const int* in_sizes, int n_in,
                              void* d_out, int out_size, void* d_ws, size_t ws_size,
                              hipStream_t stream) {
  const float* x  = (const float*)d_in[0];
  const float* wt = (const float*)d_in[1];
  const float* bs = (const float*)d_in[2];
  float* out = (float*)d_out;

  if (ws_size < WS_NEEDED) {     // safety net: direct fp32 conv
    k_naive<<<(25690112 + 255) / 256, 256, 0, stream>>>(x, wt, bs, out);
    return;
  }

  bf16_t* Xp  = (bf16_t*)d_ws;
  bf16_t* Wpk = (bf16_t*)((char*)d_ws + WPERM_OFF);

  k_pre <<<3008, 256, 0, stream>>>(x, wt, Xp, Wpk);         // xform (1856) + wperm (1152)
  k_conv<<<448, 512, 0, stream>>>(Xp, Wpk, bs, out);        // 32 img * 14 row-groups
}

// Round 14
// 76.155 us; speedup vs baseline: 15.0313x; 15.0313x over previous
//
#include <hip/hip_runtime.h>
#include <cstdint>

typedef __bf16 bf16_t;
typedef __bf16 bf16x8 __attribute__((ext_vector_type(8)));
typedef float  f32x4  __attribute__((ext_vector_type(4)));

// Workspace layout
#define XPAD_ELEMS (32UL*58*58*128)      // padded NHWC bf16 input
#define WPERM_OFF  (XPAD_ELEMS*2)        // bytes
#define WPERM_ELEMS (256UL*9*128)        // 294912
#define WS_NEEDED  (WPERM_OFF + WPERM_ELEMS*2)

// async global->LDS, 16B per lane; lds dest is wave-uniform base + lane*16
__device__ __forceinline__ void async16(const bf16_t* g, const bf16_t* l) {
  __builtin_amdgcn_global_load_lds(
      (const __attribute__((address_space(1))) void*)g,
      (__attribute__((address_space(3))) void*)l, 16, 0, 0);
}

// ------- merged prepass: x transpose (blocks 0..1855) + weight prepack (1856..3007) ----
// xform: NCHW f32 -> padded NHWC bf16 (32,58,58,128), borders zeroed.
// wperm: OIHW f32 -> Wpk[t][kc][o][e]; value = wt[o][c=ci*32+kc*8+e][tap rs], ci=t&3, rs=t>>2.
__global__ __launch_bounds__(256) void k_pre(const float* __restrict__ x,
                                             const float* __restrict__ wt,
                                             bf16_t* __restrict__ Xp,
                                             bf16_t* __restrict__ Wp) {
  const int bid = (int)blockIdx.x;
  const int t = threadIdx.x;
  if (bid >= 1856) {                      // ---- weight prepack ----
    int i = (bid - 1856) * 256 + t;
    if (i >= 294912) return;
    int e  = i & 7;
    int o  = (i >> 3) & 255;
    int kc = (i >> 11) & 3;
    int tt = i >> 13;
    int ci = tt & 3, rs = tt >> 2;
    int c  = ci * 32 + kc * 8 + e;
    Wp[i] = (bf16_t)wt[o * 1152 + c * 9 + rs];
    return;
  }
  // ---- x transform ----
  const int n = bid / 58, hp = bid % 58;
  bf16_t* drow = Xp + ((size_t)n * 58 + hp) * 58 * 128;
  uint4 z; z.x = z.y = z.z = z.w = 0;
  if (hp == 0 || hp == 57) {             // full border row
    uint4* p = (uint4*)drow;
    for (int i = t; i < 928; i += 256) p[i] = z;
    return;
  }
  if (t < 32) {                           // border pixels w=0 and w=57
    uint4* p0 = (uint4*)drow;
    uint4* p1 = (uint4*)(drow + 57 * 128);
    if (t < 16) p0[t] = z; else p1[t - 16] = z;
  }
  const int h = hp - 1;
  const float* src = x + (size_t)n * 401408 + h * 56;   // + c*3136 + w
  __shared__ float lds[128 * 57];
  for (int i = t; i < 7168; i += 256) {   // 128 c * 56 w
    int c = i / 56;
    int w = i - c * 56;
    lds[c * 57 + w] = src[(size_t)c * 3136 + w];
  }
  __syncthreads();
  bf16_t* dst = drow + 128;               // w starts at 1
  for (int i = t; i < 3584; i += 256) {   // pairs of channels
    int cp = i & 63, w = i >> 6;
    int c0 = cp * 2;
    unsigned short u0 = __builtin_bit_cast(unsigned short, (bf16_t)lds[c0 * 57 + w]);
    unsigned short u1 = __builtin_bit_cast(unsigned short, (bf16_t)lds[(c0 + 1) * 57 + w]);
    *(unsigned int*)(dst + (size_t)w * 128 + c0) = (unsigned)u0 | ((unsigned)u1 << 16);
  }
}

// ---------------- naive fp32 fallback (only if ws too small) ----------------
__global__ void k_naive(const float* __restrict__ x, const float* __restrict__ wt,
                        const float* __restrict__ bs, float* __restrict__ out) {
  int idx = blockIdx.x * 256 + threadIdx.x;
  if (idx >= 25690112) return;
  int w = idx % 56; int tmp = idx / 56;
  int h = tmp % 56; tmp /= 56;
  int k = tmp % 256; int n = tmp / 256;
  float acc = bs[k];
  for (int c = 0; c < 128; ++c)
    for (int r = 0; r < 3; ++r) {
      int hy = h + r - 1; if ((unsigned)hy >= 56u) continue;
      for (int s = 0; s < 3; ++s) {
        int wx = w + s - 1; if ((unsigned)wx >= 56u) continue;
        acc += x[((size_t)(n * 128 + c) * 56 + hy) * 56 + wx] *
               wt[((size_t)(k * 128 + c) * 3 + r) * 3 + s];
      }
    }
  out[idx] = acc;
}

// ---------------- main conv (r9 champion, verbatim): barrier-free K-loop ----------
// Block = 4 waves (256 thr); wave owns 64 out-ch x 112 px (2 output rows).
// B: 4-row padded strip (59392B) staged ONCE into LDS (chunk-XOR swizzle);
//    per-step 7 ds_read_b128 double-buffered distance-1.
// A: reg-resident, distance-2 prefetch from L2-resident Wpk (contiguous 256B runs).
// K-loop has NO barriers — waves free-run; setprio(1) wraps the MFMA cluster.
// NOTE: ratio-4 (28 MFMA : 7 ds_read) at 2 waves/SIMD is the measured optimum:
//  ratio-2@4w (r7) = 100us, ratio-4@4w (r13) = VGPR spill, per-step barriers (r5/r11) regress.
__global__ __launch_bounds__(256, 2) void k_conv(const bf16_t* __restrict__ Xp,
                                                 const bf16_t* __restrict__ Wpk,
                                                 const float* __restrict__ bias,
                                                 float* __restrict__ out) {
  __shared__ bf16_t strip[3712 * 8];      // 59392 B: [pix 4*58][chunk16][8ch]
  const int tid = threadIdx.x, lane = tid & 63, wv = tid >> 6;   // wv 0..3
  const int sid = (int)blockIdx.x;        // 0..895
  const int n   = sid / 28;
  const int h0  = (sid - n * 28) * 2;     // padded strip rows h0..h0+3

  // ---- strip staging: 14 full rounds + 128 slots (waves 0,1) ----
  const bf16_t* xrow = Xp + ((size_t)n * 58 + h0) * 58 * 128;
#pragma unroll
  for (int r = 0; r < 14; ++r) {
    int slot = r * 256 + tid;
    int pix = slot >> 4, cp = slot & 15;
    int hp = pix / 58, wp = pix - hp * 58;
    int cl = cp ^ (wp & 7);               // fetch logical chunk into phys slot
    async16(xrow + ((size_t)(hp * 58 + wp)) * 128 + cl * 8,
            strip + (r * 256 + wv * 64) * 8);
  }
  if (tid < 128) {                        // waves 0,1 fully active
    int slot = 3584 + tid;
    int pix = slot >> 4, cp = slot & 15;
    int hp = pix / 58, wp = pix - hp * 58;
    int cl = cp ^ (wp & 7);
    async16(xrow + ((size_t)(hp * 58 + wp)) * 128 + cl * 8,
            strip + (3584 + wv * 64) * 8);
  }

  // ---- per-lane geometry ----
  const int fr = lane & 15, fg = lane >> 4;
  int pixoff[7];
#pragma unroll
  for (int ni = 0; ni < 7; ++ni) {
    int pq = ni * 16 + fr;                // tile pixel 0..111
    int oh = (pq >= 56) ? 1 : 0;
    pixoff[ni] = (pq + 2 * oh) * 128;     // strip element offset of pixel
  }

  // ---- A fragment source: wave-private 64 rows, contiguous per 16-lane group ----
  const bf16_t* wsrc = Wpk + fg * 2048 + ((wv << 6) + fr) * 8;  // + t*8192 + mi*128
  bf16x8 areg[2][4];
#pragma unroll
  for (int mi = 0; mi < 4; ++mi) {
    areg[0][mi] = *(const bf16x8*)(wsrc + mi * 128);          // t=0
    areg[1][mi] = *(const bf16x8*)(wsrc + 8192 + mi * 128);   // t=1
  }

  // B-fragment base for step t (compile-time r,s,ci under full unroll):
#define BBASE(t) ((((((t) >> 2) / 3) * 58 + ((t) >> 2) % 3) * 16 +                 \
                   ((((t) & 3) * 4 + fg) ^ ((fr + ((t) >> 2) % 3) & 7))) * 8)

  __syncthreads();           // strip landed (vmcnt drain) — ONLY barrier

  f32x4 acc[4][7] = {};
  bf16x8 bcur[7], bnxt[7];
#pragma unroll
  for (int ni = 0; ni < 7; ++ni)
    bcur[ni] = *(const bf16x8*)&strip[pixoff[ni] + BBASE(0)];

#pragma unroll
  for (int t = 0; t < 36; ++t) {
    const int pb = t & 1;                 // static under full unroll
    // prefetch next step's B fragments FIRST — retire under this step's MFMAs
    if (t + 1 < 36) {
      const int nb = BBASE(t + 1);
#pragma unroll
      for (int ni = 0; ni < 7; ++ni)
        bnxt[ni] = *(const bf16x8*)&strip[pixoff[ni] + nb];
    }
    __builtin_amdgcn_s_setprio(1);
#pragma unroll
    for (int mi = 0; mi < 4; ++mi)
#pragma unroll
      for (int ni = 0; ni < 7; ++ni)
        acc[mi][ni] = __builtin_amdgcn_mfma_f32_16x16x32_bf16(areg[pb][mi], bcur[ni], acc[mi][ni], 0, 0, 0);
    __builtin_amdgcn_s_setprio(0);
    if (t + 2 < 36) {                     // distance-2 A prefetch into freed slots
#pragma unroll
      for (int mi = 0; mi < 4; ++mi)
        areg[pb][mi] = *(const bf16x8*)(wsrc + (size_t)(t + 2) * 8192 + mi * 128);
    }
#pragma unroll
    for (int ni = 0; ni < 7; ++ni)        // SSA-renamed under unroll, no copies
      bcur[ni] = bnxt[ni];
  }
#undef BBASE

  // ---- epilogue: D reg j -> k = wv*64 + mi*16 + fg*4 + j, col = pixel fr ----
  const int mbase = wv * 64;
  float bv[4][4];
#pragma unroll
  for (int mi = 0; mi < 4; ++mi)
#pragma unroll
    for (int j = 0; j < 4; ++j)
      bv[mi][j] = bias[mbase + mi * 16 + fg * 4 + j];

#pragma unroll
  for (int ni = 0; ni < 7; ++ni) {
    int pq = ni * 16 + fr;
    int oh = (pq >= 56) ? 1 : 0;
    int ow = pq - oh * 56;
    int h = h0 + oh;
    float* ob = out + (size_t)n * 802816 + h * 56 + ow;
#pragma unroll
    for (int mi = 0; mi < 4; ++mi) {
      int kb = mbase + mi * 16 + fg * 4;
#pragma unroll
      for (int j = 0; j < 4; ++j)
        ob[(size_t)(kb + j) * 3136] = acc[mi][ni][j] + bv[mi][j];
    }
  }
}

extern "C" void kernel_launch(void* const* d_in, const int* in_sizes, int n_in,
                              void* d_out, int out_size, void* d_ws, size_t ws_size,
                              hipStream_t stream) {
  const float* x  = (const float*)d_in[0];
  const float* wt = (const float*)d_in[1];
  const float* bs = (const float*)d_in[2];
  float* out = (float*)d_out;

  if (ws_size < WS_NEEDED) {     // safety net: direct fp32 conv
    k_naive<<<(25690112 + 255) / 256, 256, 0, stream>>>(x, wt, bs, out);
    return;
  }

  bf16_t* Xp  = (bf16_t*)d_ws;
  bf16_t* Wpk = (bf16_t*)((char*)d_ws + WPERM_OFF);

  k_pre <<<3008, 256, 0, stream>>>(x, wt, Xp, Wpk);         // xform (1856) + wperm (1152)
  k_conv<<<896, 256, 0, stream>>>(Xp, Wpk, bs, out);        // 32 img * 28 strips
}